// Round 2
// baseline (149.935 us; speedup 1.0000x reference)
//
#include <hip/hip_runtime.h>

// One wave (64 lanes) per batch.
// k_proj: Wk in per-lane registers, coalesced k-row loads, DPP reduce (VALU pipe).
// Downstream: lane-owns-row in registers; LDS used only for broadcasts/transposes
// (uniform-address b128 reads = no bank conflicts, few instructions).

#define DPP_ADD(x, ctrl, rmask)                                                   \
  x += __int_as_float(__builtin_amdgcn_update_dpp(                                \
      0, __float_as_int(x), ctrl, rmask, 0xF, false))

__device__ __forceinline__ float wave_sum64(float x) {
  DPP_ADD(x, 0xB1, 0xF);   // xor 1
  DPP_ADD(x, 0x4E, 0xF);   // xor 2
  DPP_ADD(x, 0x141, 0xF);  // xor 4
  DPP_ADD(x, 0x140, 0xF);  // xor 8
  DPP_ADD(x, 0x142, 0xA);  // row_bcast15
  DPP_ADD(x, 0x143, 0xC);  // row_bcast31
  return x;                // full sum valid in lanes 48..63
}

// Butterfly reductions within each 32-lane half; every lane gets the result.
#define DPP_BF(x, OP, ctrl)                                                       \
  {                                                                               \
    float _t = __int_as_float(__builtin_amdgcn_update_dpp(                        \
        0, __float_as_int(x), ctrl, 0xF, 0xF, true));                             \
    x = OP(x, _t);                                                                \
  }
__device__ __forceinline__ float bf32_max(float x) {
  DPP_BF(x, fmaxf, 0xB1);
  DPP_BF(x, fmaxf, 0x4E);
  DPP_BF(x, fmaxf, 0x141);
  DPP_BF(x, fmaxf, 0x140);
  float t = __int_as_float(__builtin_amdgcn_ds_swizzle(__float_as_int(x), 0x401F));
  return fmaxf(x, t);
}
__device__ __forceinline__ float bf32_add(float x) {
  DPP_ADD(x, 0xB1, 0xF);
  DPP_ADD(x, 0x4E, 0xF);
  DPP_ADD(x, 0x141, 0xF);
  DPP_ADD(x, 0x140, 0xF);
  float t = __int_as_float(__builtin_amdgcn_ds_swizzle(__float_as_int(x), 0x401F));
  return x + t;
}

__device__ __forceinline__ float dot12(const float* a, float4 b0, float4 b1, float4 b2) {
  return a[0] * b0.x + a[1] * b0.y + a[2] * b0.z + a[3] * b0.w +
         a[4] * b1.x + a[5] * b1.y + a[6] * b1.z + a[7] * b1.w +
         a[8] * b2.x + a[9] * b2.y + a[10] * b2.z + a[11] * b2.w;
}

__global__ __launch_bounds__(64) void coattn_kernel(
    const float* __restrict__ q, const float* __restrict__ k,
    const float* __restrict__ Wq, const float* __restrict__ bq,
    const float* __restrict__ Wk, const float* __restrict__ bk,
    const float* __restrict__ Wl, const float* __restrict__ bl,
    float* __restrict__ out) {
  constexpr int QL = 24, KVL = 24, DQ = 12, DKV = 512;

  __shared__ alignas(16) float kp[KVL][DQ];    // k_proj (no bias)
  __shared__ alignas(16) float qc[QL][24];     // [q | c_q]
  __shared__ alignas(16) float akT[KVL][28];   // akT[k][q] = a_k[q][k]
  __shared__ alignas(16) float ckL[KVL][28];   // ckL[k][e]
  __shared__ alignas(16) float WqL[DQ][DQ];    // Wq[e][d]
  __shared__ alignas(16) float WlT[KVL][DQ];   // WlT[k][d] = Wl[d][k]
  __shared__ alignas(16) float bqL[DQ], bkL[DQ], blL[DQ];

  const int lane = threadIdx.x;
  const int b = blockIdx.x;
  const int li = (lane < 24) ? lane : 0;  // row ownership index (clamped)

  // ---------------- init staging ----------------
  for (int p = lane; p < DQ * DQ; p += 64) WqL[p / DQ][p % DQ] = Wq[p];
  for (int p = lane; p < DQ * KVL; p += 64) WlT[p % KVL][p / KVL] = Wl[p];
  const float* qb = q + (size_t)b * (QL * DQ);
  for (int p = lane; p < QL * DQ; p += 64) qc[p / DQ][p % DQ] = qb[p];
  if (lane < DQ) {
    bqL[lane] = bq[lane];
    bkL[lane] = bk[lane];
    blL[lane] = bl[lane];
  }

  // ---------------- Wk into registers ----------------
  const float4* WkV = reinterpret_cast<const float4*>(Wk);
  float4 wk0[DQ], wk1[DQ];
#pragma unroll
  for (int e = 0; e < DQ; ++e) {
    wk0[e] = WkV[e * 128 + lane];
    wk1[e] = WkV[e * 128 + 64 + lane];
  }

  // ---------------- k_proj (bias folded downstream) ----------------
  const float4* kbV = reinterpret_cast<const float4*>(k + (size_t)b * (KVL * DKV));
  float4 ca = kbV[lane];
  float4 cb = kbV[64 + lane];
  for (int kv = 0; kv < KVL; ++kv) {
    const int nkv = (kv + 1 < KVL) ? kv + 1 : kv;
    float4 na = kbV[nkv * 128 + lane];
    float4 nb = kbV[nkv * 128 + 64 + lane];
    float pp[DQ];
#pragma unroll
    for (int e = 0; e < DQ; ++e) {
      pp[e] = ca.x * wk0[e].x + ca.y * wk0[e].y + ca.z * wk0[e].z + ca.w * wk0[e].w +
              cb.x * wk1[e].x + cb.y * wk1[e].y + cb.z * wk1[e].z + cb.w * wk1[e].w;
    }
#pragma unroll
    for (int e = 0; e < DQ; ++e) pp[e] = wave_sum64(pp[e]);
    if (lane == 63) {
      float4 w0, w1, w2;
      w0.x = pp[0]; w0.y = pp[1]; w0.z = pp[2]; w0.w = pp[3];
      w1.x = pp[4]; w1.y = pp[5]; w1.z = pp[6]; w1.w = pp[7];
      w2.x = pp[8]; w2.y = pp[9]; w2.z = pp[10]; w2.w = pp[11];
      *(float4*)&kp[kv][0] = w0;
      *(float4*)&kp[kv][4] = w1;
      *(float4*)&kp[kv][8] = w2;
    }
    ca = na;
    cb = nb;
  }

  // ---------------- q_proj (lane li owns q-row li) ----------------
  float qr[DQ];
  {
    float4 t0 = *(const float4*)&qc[li][0];
    float4 t1 = *(const float4*)&qc[li][4];
    float4 t2 = *(const float4*)&qc[li][8];
    qr[0] = t0.x; qr[1] = t0.y; qr[2] = t0.z; qr[3] = t0.w;
    qr[4] = t1.x; qr[5] = t1.y; qr[6] = t1.z; qr[7] = t1.w;
    qr[8] = t2.x; qr[9] = t2.y; qr[10] = t2.z; qr[11] = t2.w;
  }
  float bqr[DQ];
  {
    float4 t0 = *(const float4*)&bqL[0];
    float4 t1 = *(const float4*)&bqL[4];
    float4 t2 = *(const float4*)&bqL[8];
    bqr[0] = t0.x; bqr[1] = t0.y; bqr[2] = t0.z; bqr[3] = t0.w;
    bqr[4] = t1.x; bqr[5] = t1.y; bqr[6] = t1.z; bqr[7] = t1.w;
    bqr[8] = t2.x; bqr[9] = t2.y; bqr[10] = t2.z; bqr[11] = t2.w;
  }
  float qp_[DQ];
#pragma unroll
  for (int e = 0; e < DQ; ++e) {
    float4 w0 = *(const float4*)&WqL[e][0];
    float4 w1 = *(const float4*)&WqL[e][4];
    float4 w2 = *(const float4*)&WqL[e][8];
    qp_[e] = bqr[e] + dot12(qr, w0, w1, w2);
  }

  // bk into registers (for bias folding)
  float bkr[DQ];
  {
    float4 t0 = *(const float4*)&bkL[0];
    float4 t1 = *(const float4*)&bkL[4];
    float4 t2 = *(const float4*)&bkL[8];
    bkr[0] = t0.x; bkr[1] = t0.y; bkr[2] = t0.z; bkr[3] = t0.w;
    bkr[4] = t1.x; bkr[5] = t1.y; bkr[6] = t1.z; bkr[7] = t1.w;
    bkr[8] = t2.x; bkr[9] = t2.y; bkr[10] = t2.z; bkr[11] = t2.w;
  }
  float qbk = 0.f;
#pragma unroll
  for (int e = 0; e < DQ; ++e) qbk += qp_[e] * bkr[e];

  // ---------------- qk row: qk[li][kk] = dot(q_proj, k_proj+bk) ----------------
  float qkr[KVL];
#pragma unroll
  for (int kk = 0; kk < KVL; ++kk) {
    float4 k0 = *(const float4*)&kp[kk][0];
    float4 k1 = *(const float4*)&kp[kk][4];
    float4 k2 = *(const float4*)&kp[kk][8];
    qkr[kk] = qbk + dot12(qp_, k0, k1, k2);
  }
  // neutralize pad lanes 24..31 for the column butterflies
  if (lane >= 24 && lane < 32) {
#pragma unroll
    for (int j = 0; j < KVL; ++j) qkr[j] = -1e30f;
  }

  // ---------------- a_k: softmax over kk (registers, per lane) ----------------
  float akr[KVL];
  {
    float rm = qkr[0];
#pragma unroll
    for (int j = 1; j < KVL; ++j) rm = fmaxf(rm, qkr[j]);
    float s = 0.f;
#pragma unroll
    for (int j = 0; j < KVL; ++j) {
      akr[j] = __expf(qkr[j] - rm);
      s += akr[j];
    }
    const float inv = __builtin_amdgcn_rcpf(s);
#pragma unroll
    for (int j = 0; j < KVL; ++j) akr[j] *= inv;
  }

  // ---------------- a_q: softmax over q (cross-lane butterflies); in-place ----
#pragma unroll
  for (int j = 0; j < KVL; ++j) {
    const float m = bf32_max(qkr[j]);
    const float t = __expf(qkr[j] - m);
    const float s2 = bf32_add(t);
    qkr[j] = t * __builtin_amdgcn_rcpf(s2);  // qkr now holds the a_q row
  }

  // ---------------- c_q[li][e] = sum_k a_q*kp[k][e] + bk[e]*sum_k a_q ----------
  float sa = 0.f;
#pragma unroll
  for (int j = 0; j < KVL; ++j) sa += qkr[j];
  float cq[DQ];
#pragma unroll
  for (int e = 0; e < DQ; ++e) cq[e] = bkr[e] * sa;
#pragma unroll
  for (int kk = 0; kk < KVL; ++kk) {
    float4 k0 = *(const float4*)&kp[kk][0];
    float4 k1 = *(const float4*)&kp[kk][4];
    float4 k2 = *(const float4*)&kp[kk][8];
    const float a = qkr[kk];
    cq[0] += a * k0.x; cq[1] += a * k0.y; cq[2] += a * k0.z; cq[3] += a * k0.w;
    cq[4] += a * k1.x; cq[5] += a * k1.y; cq[6] += a * k1.z; cq[7] += a * k1.w;
    cq[8] += a * k2.x; cq[9] += a * k2.y; cq[10] += a * k2.z; cq[11] += a * k2.w;
  }
  if (lane < 24) {
    float4 w0, w1, w2;
    w0.x = cq[0]; w0.y = cq[1]; w0.z = cq[2]; w0.w = cq[3];
    w1.x = cq[4]; w1.y = cq[5]; w1.z = cq[6]; w1.w = cq[7];
    w2.x = cq[8]; w2.y = cq[9]; w2.z = cq[10]; w2.w = cq[11];
    *(float4*)&qc[li][12] = w0;
    *(float4*)&qc[li][16] = w1;
    *(float4*)&qc[li][20] = w2;
#pragma unroll
    for (int kk = 0; kk < KVL; ++kk) akT[kk][li] = akr[kk];
  }

  // ---------------- c_k[li][e] = sum_q a_k[q][li]*qc[q][e] ----------------
  float ak[QL];
  {
    float4 a0 = *(const float4*)&akT[li][0];
    float4 a1 = *(const float4*)&akT[li][4];
    float4 a2 = *(const float4*)&akT[li][8];
    float4 a3 = *(const float4*)&akT[li][12];
    float4 a4 = *(const float4*)&akT[li][16];
    float4 a5 = *(const float4*)&akT[li][20];
    ak[0] = a0.x; ak[1] = a0.y; ak[2] = a0.z; ak[3] = a0.w;
    ak[4] = a1.x; ak[5] = a1.y; ak[6] = a1.z; ak[7] = a1.w;
    ak[8] = a2.x; ak[9] = a2.y; ak[10] = a2.z; ak[11] = a2.w;
    ak[12] = a3.x; ak[13] = a3.y; ak[14] = a3.z; ak[15] = a3.w;
    ak[16] = a4.x; ak[17] = a4.y; ak[18] = a4.z; ak[19] = a4.w;
    ak[20] = a5.x; ak[21] = a5.y; ak[22] = a5.z; ak[23] = a5.w;
  }
  float ck[24];
#pragma unroll
  for (int e = 0; e < 24; ++e) ck[e] = 0.f;
#pragma unroll
  for (int qq = 0; qq < QL; ++qq) {
    float4 c0 = *(const float4*)&qc[qq][0];
    float4 c1 = *(const float4*)&qc[qq][4];
    float4 c2 = *(const float4*)&qc[qq][8];
    float4 c3 = *(const float4*)&qc[qq][12];
    float4 c4 = *(const float4*)&qc[qq][16];
    float4 c5 = *(const float4*)&qc[qq][20];
    const float a = ak[qq];
    ck[0] += a * c0.x; ck[1] += a * c0.y; ck[2] += a * c0.z; ck[3] += a * c0.w;
    ck[4] += a * c1.x; ck[5] += a * c1.y; ck[6] += a * c1.z; ck[7] += a * c1.w;
    ck[8] += a * c2.x; ck[9] += a * c2.y; ck[10] += a * c2.z; ck[11] += a * c2.w;
    ck[12] += a * c3.x; ck[13] += a * c3.y; ck[14] += a * c3.z; ck[15] += a * c3.w;
    ck[16] += a * c4.x; ck[17] += a * c4.y; ck[18] += a * c4.z; ck[19] += a * c4.w;
    ck[20] += a * c5.x; ck[21] += a * c5.y; ck[22] += a * c5.z; ck[23] += a * c5.w;
  }
  if (lane < 24) {
    float4 w0, w1, w2, w3, w4, w5;
    w0.x = ck[0]; w0.y = ck[1]; w0.z = ck[2]; w0.w = ck[3];
    w1.x = ck[4]; w1.y = ck[5]; w1.z = ck[6]; w1.w = ck[7];
    w2.x = ck[8]; w2.y = ck[9]; w2.z = ck[10]; w2.w = ck[11];
    w3.x = ck[12]; w3.y = ck[13]; w3.z = ck[14]; w3.w = ck[15];
    w4.x = ck[16]; w4.y = ck[17]; w4.z = ck[18]; w4.w = ck[19];
    w5.x = ck[20]; w5.y = ck[21]; w5.z = ck[22]; w5.w = ck[23];
    *(float4*)&ckL[li][0] = w0;
    *(float4*)&ckL[li][4] = w1;
    *(float4*)&ckL[li][8] = w2;
    *(float4*)&ckL[li][12] = w3;
    *(float4*)&ckL[li][16] = w4;
    *(float4*)&ckL[li][20] = w5;
  }

  // ---------------- attn[e][d] = bl[d] + sum_k c_k[k][e]*Wl[d][k] -------------
  float acc[DQ];
  {
    float4 t0 = *(const float4*)&blL[0];
    float4 t1 = *(const float4*)&blL[4];
    float4 t2 = *(const float4*)&blL[8];
    acc[0] = t0.x; acc[1] = t0.y; acc[2] = t0.z; acc[3] = t0.w;
    acc[4] = t1.x; acc[5] = t1.y; acc[6] = t1.z; acc[7] = t1.w;
    acc[8] = t2.x; acc[9] = t2.y; acc[10] = t2.z; acc[11] = t2.w;
  }
#pragma unroll
  for (int kk = 0; kk < KVL; ++kk) {
    const float cv = ckL[kk][li];
    float4 w0 = *(const float4*)&WlT[kk][0];
    float4 w1 = *(const float4*)&WlT[kk][4];
    float4 w2 = *(const float4*)&WlT[kk][8];
    acc[0] += cv * w0.x; acc[1] += cv * w0.y; acc[2] += cv * w0.z; acc[3] += cv * w0.w;
    acc[4] += cv * w1.x; acc[5] += cv * w1.y; acc[6] += cv * w1.z; acc[7] += cv * w1.w;
    acc[8] += cv * w2.x; acc[9] += cv * w2.y; acc[10] += cv * w2.z; acc[11] += cv * w2.w;
  }
  if (lane < 24) {
    float* ob = out + (size_t)b * 288 + li * 12;
    float4 w0, w1, w2;
    w0.x = acc[0]; w0.y = acc[1]; w0.z = acc[2]; w0.w = acc[3];
    w1.x = acc[4]; w1.y = acc[5]; w1.z = acc[6]; w1.w = acc[7];
    w2.x = acc[8]; w2.y = acc[9]; w2.z = acc[10]; w2.w = acc[11];
    *(float4*)(ob + 0) = w0;
    *(float4*)(ob + 4) = w1;
    *(float4*)(ob + 8) = w2;
  }
}

extern "C" void kernel_launch(void* const* d_in, const int* in_sizes, int n_in,
                              void* d_out, int out_size, void* d_ws, size_t ws_size,
                              hipStream_t stream) {
  const float* q = (const float*)d_in[0];
  const float* k = (const float*)d_in[1];
  // d_in[2] = v : unused by the reference
  const float* Wq = (const float*)d_in[3];
  const float* bq = (const float*)d_in[4];
  const float* Wk = (const float*)d_in[5];
  const float* bk = (const float*)d_in[6];
  const float* Wl = (const float*)d_in[7];
  const float* bl = (const float*)d_in[8];
  float* out = (float*)d_out;

  const int B = in_sizes[0] / (24 * 12);
  coattn_kernel<<<B, 64, 0, stream>>>(q, k, Wq, bq, Wk, bk, Wl, bl, out);
}

// Round 3
// 129.443 us; speedup vs baseline: 1.1583x; 1.1583x over previous
//
#include <hip/hip_runtime.h>

// One wave (64 lanes) per batch.
// k_proj: Wk in per-lane registers, coalesced k-row loads with DEPTH-2 prefetch
// (4-slot ping-pong, no rotation movs -> no per-iteration vmcnt(0) drain),
// DPP reduce on the VALU pipe. Downstream: lane-owns-row in registers.

#define DPP_ADD(x, ctrl, rmask)                                                   \
  x += __int_as_float(__builtin_amdgcn_update_dpp(                                \
      0, __float_as_int(x), ctrl, rmask, 0xF, false))

__device__ __forceinline__ float wave_sum64(float x) {
  DPP_ADD(x, 0xB1, 0xF);   // xor 1
  DPP_ADD(x, 0x4E, 0xF);   // xor 2
  DPP_ADD(x, 0x141, 0xF);  // xor 4
  DPP_ADD(x, 0x140, 0xF);  // xor 8
  DPP_ADD(x, 0x142, 0xA);  // row_bcast15
  DPP_ADD(x, 0x143, 0xC);  // row_bcast31
  return x;                // full sum valid in lanes 48..63
}

#define DPP_BF(x, OP, ctrl)                                                       \
  {                                                                               \
    float _t = __int_as_float(__builtin_amdgcn_update_dpp(                        \
        0, __float_as_int(x), ctrl, 0xF, 0xF, true));                             \
    x = OP(x, _t);                                                                \
  }
__device__ __forceinline__ float bf32_max(float x) {
  DPP_BF(x, fmaxf, 0xB1);
  DPP_BF(x, fmaxf, 0x4E);
  DPP_BF(x, fmaxf, 0x141);
  DPP_BF(x, fmaxf, 0x140);
  float t = __int_as_float(__builtin_amdgcn_ds_swizzle(__float_as_int(x), 0x401F));
  return fmaxf(x, t);
}
__device__ __forceinline__ float bf32_add(float x) {
  DPP_ADD(x, 0xB1, 0xF);
  DPP_ADD(x, 0x4E, 0xF);
  DPP_ADD(x, 0x141, 0xF);
  DPP_ADD(x, 0x140, 0xF);
  float t = __int_as_float(__builtin_amdgcn_ds_swizzle(__float_as_int(x), 0x401F));
  return x + t;
}

__device__ __forceinline__ float dot12(const float* a, float4 b0, float4 b1, float4 b2) {
  return a[0] * b0.x + a[1] * b0.y + a[2] * b0.z + a[3] * b0.w +
         a[4] * b1.x + a[5] * b1.y + a[6] * b1.z + a[7] * b1.w +
         a[8] * b2.x + a[9] * b2.y + a[10] * b2.z + a[11] * b2.w;
}

__global__ __launch_bounds__(64) void coattn_kernel(
    const float* __restrict__ q, const float* __restrict__ k,
    const float* __restrict__ Wq, const float* __restrict__ bq,
    const float* __restrict__ Wk, const float* __restrict__ bk,
    const float* __restrict__ Wl, const float* __restrict__ bl,
    float* __restrict__ out) {
  constexpr int QL = 24, KVL = 24, DQ = 12, DKV = 512;

  __shared__ alignas(16) float kp[KVL][DQ];    // k_proj (no bias)
  __shared__ alignas(16) float qc[QL][24];     // [q | c_q]
  __shared__ alignas(16) float akT[KVL][28];   // akT[k][q] = a_k[q][k]
  __shared__ alignas(16) float ckL[KVL][28];   // ckL[k][e]
  __shared__ alignas(16) float WqL[DQ][DQ];    // Wq[e][d]
  __shared__ alignas(16) float WlT[KVL][DQ];   // WlT[k][d] = Wl[d][k]
  __shared__ alignas(16) float bqL[DQ], bkL[DQ], blL[DQ];

  const int lane = threadIdx.x;
  const int b = blockIdx.x;
  const int li = (lane < 24) ? lane : 0;  // row ownership index (clamped)

  // ---------------- init staging ----------------
  for (int p = lane; p < DQ * DQ; p += 64) WqL[p / DQ][p % DQ] = Wq[p];
  for (int p = lane; p < DQ * KVL; p += 64) WlT[p % KVL][p / KVL] = Wl[p];
  const float* qb = q + (size_t)b * (QL * DQ);
  for (int p = lane; p < QL * DQ; p += 64) qc[p / DQ][p % DQ] = qb[p];
  if (lane < DQ) {
    bqL[lane] = bq[lane];
    bkL[lane] = bk[lane];
    blL[lane] = bl[lane];
  }

  // ---------------- Wk into registers ----------------
  const float4* WkV = reinterpret_cast<const float4*>(Wk);
  float4 wk0[DQ], wk1[DQ];
#pragma unroll
  for (int e = 0; e < DQ; ++e) {
    wk0[e] = WkV[e * 128 + lane];
    wk1[e] = WkV[e * 128 + 64 + lane];
  }

  // ---------------- k_proj: depth-2 prefetch, 4-slot ping-pong ----------------
  const float4* kbV = reinterpret_cast<const float4*>(k + (size_t)b * (KVL * DKV));

#define KROW(AC, BC, ROW)                                                          \
  {                                                                                \
    float pp[DQ];                                                                  \
    _Pragma("unroll") for (int e = 0; e < DQ; ++e) {                               \
      pp[e] = (AC).x * wk0[e].x + (AC).y * wk0[e].y + (AC).z * wk0[e].z +          \
              (AC).w * wk0[e].w + (BC).x * wk1[e].x + (BC).y * wk1[e].y +          \
              (BC).z * wk1[e].z + (BC).w * wk1[e].w;                               \
    }                                                                              \
    _Pragma("unroll") for (int e = 0; e < DQ; ++e) pp[e] = wave_sum64(pp[e]);      \
    if (lane == 63) {                                                              \
      float4 w0, w1, w2;                                                           \
      w0.x = pp[0]; w0.y = pp[1]; w0.z = pp[2]; w0.w = pp[3];                      \
      w1.x = pp[4]; w1.y = pp[5]; w1.z = pp[6]; w1.w = pp[7];                      \
      w2.x = pp[8]; w2.y = pp[9]; w2.z = pp[10]; w2.w = pp[11];                    \
      *(float4*)&kp[ROW][0] = w0;                                                  \
      *(float4*)&kp[ROW][4] = w1;                                                  \
      *(float4*)&kp[ROW][8] = w2;                                                  \
    }                                                                              \
  }

  float4 A0 = kbV[0 * 128 + lane], B0 = kbV[0 * 128 + 64 + lane];
  float4 A1 = kbV[1 * 128 + lane], B1 = kbV[1 * 128 + 64 + lane];
  float4 A2, B2, A3, B3;
  for (int kv = 0; kv < KVL; kv += 4) {
    // j=0: issue row kv+2 -> slot2; compute row kv from slot0
    {
      const int r = kv + 2;  // kv in {0,..,20}: kv+2 <= 22 < 24, always valid
      A2 = kbV[r * 128 + lane];
      B2 = kbV[r * 128 + 64 + lane];
    }
    KROW(A0, B0, kv);
    // j=1: issue row kv+3 -> slot3; compute row kv+1 from slot1
    {
      const int r = kv + 3;  // <= 23, always valid
      A3 = kbV[r * 128 + lane];
      B3 = kbV[r * 128 + 64 + lane];
    }
    KROW(A1, B1, kv + 1);
    // j=2: issue row kv+4 (clamped) -> slot0; compute row kv+2 from slot2
    {
      const int r = (kv + 4 < KVL) ? kv + 4 : KVL - 1;
      A0 = kbV[r * 128 + lane];
      B0 = kbV[r * 128 + 64 + lane];
    }
    KROW(A2, B2, kv + 2);
    // j=3: issue row kv+5 (clamped) -> slot1; compute row kv+3 from slot3
    {
      const int r = (kv + 5 < KVL) ? kv + 5 : KVL - 1;
      A1 = kbV[r * 128 + lane];
      B1 = kbV[r * 128 + 64 + lane];
    }
    KROW(A3, B3, kv + 3);
  }
#undef KROW

  // ---------------- q_proj (lane li owns q-row li) ----------------
  float qr[DQ];
  {
    float4 t0 = *(const float4*)&qc[li][0];
    float4 t1 = *(const float4*)&qc[li][4];
    float4 t2 = *(const float4*)&qc[li][8];
    qr[0] = t0.x; qr[1] = t0.y; qr[2] = t0.z; qr[3] = t0.w;
    qr[4] = t1.x; qr[5] = t1.y; qr[6] = t1.z; qr[7] = t1.w;
    qr[8] = t2.x; qr[9] = t2.y; qr[10] = t2.z; qr[11] = t2.w;
  }
  float bqr[DQ];
  {
    float4 t0 = *(const float4*)&bqL[0];
    float4 t1 = *(const float4*)&bqL[4];
    float4 t2 = *(const float4*)&bqL[8];
    bqr[0] = t0.x; bqr[1] = t0.y; bqr[2] = t0.z; bqr[3] = t0.w;
    bqr[4] = t1.x; bqr[5] = t1.y; bqr[6] = t1.z; bqr[7] = t1.w;
    bqr[8] = t2.x; bqr[9] = t2.y; bqr[10] = t2.z; bqr[11] = t2.w;
  }
  float qp_[DQ];
#pragma unroll
  for (int e = 0; e < DQ; ++e) {
    float4 w0 = *(const float4*)&WqL[e][0];
    float4 w1 = *(const float4*)&WqL[e][4];
    float4 w2 = *(const float4*)&WqL[e][8];
    qp_[e] = bqr[e] + dot12(qr, w0, w1, w2);
  }

  float bkr[DQ];
  {
    float4 t0 = *(const float4*)&bkL[0];
    float4 t1 = *(const float4*)&bkL[4];
    float4 t2 = *(const float4*)&bkL[8];
    bkr[0] = t0.x; bkr[1] = t0.y; bkr[2] = t0.z; bkr[3] = t0.w;
    bkr[4] = t1.x; bkr[5] = t1.y; bkr[6] = t1.z; bkr[7] = t1.w;
    bkr[8] = t2.x; bkr[9] = t2.y; bkr[10] = t2.z; bkr[11] = t2.w;
  }
  float qbk = 0.f;
#pragma unroll
  for (int e = 0; e < DQ; ++e) qbk += qp_[e] * bkr[e];

  // ---------------- qk row: qk[li][kk] = dot(q_proj, k_proj+bk) ----------------
  float qkr[KVL];
#pragma unroll
  for (int kk = 0; kk < KVL; ++kk) {
    float4 k0 = *(const float4*)&kp[kk][0];
    float4 k1 = *(const float4*)&kp[kk][4];
    float4 k2 = *(const float4*)&kp[kk][8];
    qkr[kk] = qbk + dot12(qp_, k0, k1, k2);
  }
  if (lane >= 24 && lane < 32) {
#pragma unroll
    for (int j = 0; j < KVL; ++j) qkr[j] = -1e30f;
  }

  // ---------------- a_k: softmax over kk (registers, per lane) ----------------
  float akr[KVL];
  {
    float rm = qkr[0];
#pragma unroll
    for (int j = 1; j < KVL; ++j) rm = fmaxf(rm, qkr[j]);
    float s = 0.f;
#pragma unroll
    for (int j = 0; j < KVL; ++j) {
      akr[j] = __expf(qkr[j] - rm);
      s += akr[j];
    }
    const float inv = __builtin_amdgcn_rcpf(s);
#pragma unroll
    for (int j = 0; j < KVL; ++j) akr[j] *= inv;
  }

  // ---------------- a_q: softmax over q (cross-lane butterflies) --------------
#pragma unroll
  for (int j = 0; j < KVL; ++j) {
    const float m = bf32_max(qkr[j]);
    const float t = __expf(qkr[j] - m);
    const float s2 = bf32_add(t);
    qkr[j] = t * __builtin_amdgcn_rcpf(s2);  // qkr now holds the a_q row
  }

  // ---------------- c_q[li][e] = sum_k a_q*kp[k][e] + bk[e]*sum_k a_q ----------
  float sa = 0.f;
#pragma unroll
  for (int j = 0; j < KVL; ++j) sa += qkr[j];
  float cq[DQ];
#pragma unroll
  for (int e = 0; e < DQ; ++e) cq[e] = bkr[e] * sa;
#pragma unroll
  for (int kk = 0; kk < KVL; ++kk) {
    float4 k0 = *(const float4*)&kp[kk][0];
    float4 k1 = *(const float4*)&kp[kk][4];
    float4 k2 = *(const float4*)&kp[kk][8];
    const float a = qkr[kk];
    cq[0] += a * k0.x; cq[1] += a * k0.y; cq[2] += a * k0.z; cq[3] += a * k0.w;
    cq[4] += a * k1.x; cq[5] += a * k1.y; cq[6] += a * k1.z; cq[7] += a * k1.w;
    cq[8] += a * k2.x; cq[9] += a * k2.y; cq[10] += a * k2.z; cq[11] += a * k2.w;
  }
  if (lane < 24) {
    float4 w0, w1, w2;
    w0.x = cq[0]; w0.y = cq[1]; w0.z = cq[2]; w0.w = cq[3];
    w1.x = cq[4]; w1.y = cq[5]; w1.z = cq[6]; w1.w = cq[7];
    w2.x = cq[8]; w2.y = cq[9]; w2.z = cq[10]; w2.w = cq[11];
    *(float4*)&qc[li][12] = w0;
    *(float4*)&qc[li][16] = w1;
    *(float4*)&qc[li][20] = w2;
#pragma unroll
    for (int kk = 0; kk < KVL; ++kk) akT[kk][li] = akr[kk];
  }

  // ---------------- c_k[li][e] = sum_q a_k[q][li]*qc[q][e] ----------------
  float ak[QL];
  {
    float4 a0 = *(const float4*)&akT[li][0];
    float4 a1 = *(const float4*)&akT[li][4];
    float4 a2 = *(const float4*)&akT[li][8];
    float4 a3 = *(const float4*)&akT[li][12];
    float4 a4 = *(const float4*)&akT[li][16];
    float4 a5 = *(const float4*)&akT[li][20];
    ak[0] = a0.x; ak[1] = a0.y; ak[2] = a0.z; ak[3] = a0.w;
    ak[4] = a1.x; ak[5] = a1.y; ak[6] = a1.z; ak[7] = a1.w;
    ak[8] = a2.x; ak[9] = a2.y; ak[10] = a2.z; ak[11] = a2.w;
    ak[12] = a3.x; ak[13] = a3.y; ak[14] = a3.z; ak[15] = a3.w;
    ak[16] = a4.x; ak[17] = a4.y; ak[18] = a4.z; ak[19] = a4.w;
    ak[20] = a5.x; ak[21] = a5.y; ak[22] = a5.z; ak[23] = a5.w;
  }
  float ck[24];
#pragma unroll
  for (int e = 0; e < 24; ++e) ck[e] = 0.f;
#pragma unroll
  for (int qq = 0; qq < QL; ++qq) {
    float4 c0 = *(const float4*)&qc[qq][0];
    float4 c1 = *(const float4*)&qc[qq][4];
    float4 c2 = *(const float4*)&qc[qq][8];
    float4 c3 = *(const float4*)&qc[qq][12];
    float4 c4 = *(const float4*)&qc[qq][16];
    float4 c5 = *(const float4*)&qc[qq][20];
    const float a = ak[qq];
    ck[0] += a * c0.x; ck[1] += a * c0.y; ck[2] += a * c0.z; ck[3] += a * c0.w;
    ck[4] += a * c1.x; ck[5] += a * c1.y; ck[6] += a * c1.z; ck[7] += a * c1.w;
    ck[8] += a * c2.x; ck[9] += a * c2.y; ck[10] += a * c2.z; ck[11] += a * c2.w;
    ck[12] += a * c3.x; ck[13] += a * c3.y; ck[14] += a * c3.z; ck[15] += a * c3.w;
    ck[16] += a * c4.x; ck[17] += a * c4.y; ck[18] += a * c4.z; ck[19] += a * c4.w;
    ck[20] += a * c5.x; ck[21] += a * c5.y; ck[22] += a * c5.z; ck[23] += a * c5.w;
  }
  if (lane < 24) {
    float4 w0, w1, w2, w3, w4, w5;
    w0.x = ck[0]; w0.y = ck[1]; w0.z = ck[2]; w0.w = ck[3];
    w1.x = ck[4]; w1.y = ck[5]; w1.z = ck[6]; w1.w = ck[7];
    w2.x = ck[8]; w2.y = ck[9]; w2.z = ck[10]; w2.w = ck[11];
    w3.x = ck[12]; w3.y = ck[13]; w3.z = ck[14]; w3.w = ck[15];
    w4.x = ck[16]; w4.y = ck[17]; w4.z = ck[18]; w4.w = ck[19];
    w5.x = ck[20]; w5.y = ck[21]; w5.z = ck[22]; w5.w = ck[23];
    *(float4*)&ckL[li][0] = w0;
    *(float4*)&ckL[li][4] = w1;
    *(float4*)&ckL[li][8] = w2;
    *(float4*)&ckL[li][12] = w3;
    *(float4*)&ckL[li][16] = w4;
    *(float4*)&ckL[li][20] = w5;
  }

  // ---------------- attn[e][d] = bl[d] + sum_k c_k[k][e]*Wl[d][k] -------------
  float acc[DQ];
  {
    float4 t0 = *(const float4*)&blL[0];
    float4 t1 = *(const float4*)&blL[4];
    float4 t2 = *(const float4*)&blL[8];
    acc[0] = t0.x; acc[1] = t0.y; acc[2] = t0.z; acc[3] = t0.w;
    acc[4] = t1.x; acc[5] = t1.y; acc[6] = t1.z; acc[7] = t1.w;
    acc[8] = t2.x; acc[9] = t2.y; acc[10] = t2.z; acc[11] = t2.w;
  }
#pragma unroll
  for (int kk = 0; kk < KVL; ++kk) {
    const float cv = ckL[kk][li];
    float4 w0 = *(const float4*)&WlT[kk][0];
    float4 w1 = *(const float4*)&WlT[kk][4];
    float4 w2 = *(const float4*)&WlT[kk][8];
    acc[0] += cv * w0.x; acc[1] += cv * w0.y; acc[2] += cv * w0.z; acc[3] += cv * w0.w;
    acc[4] += cv * w1.x; acc[5] += cv * w1.y; acc[6] += cv * w1.z; acc[7] += cv * w1.w;
    acc[8] += cv * w2.x; acc[9] += cv * w2.y; acc[10] += cv * w2.z; acc[11] += cv * w2.w;
  }
  if (lane < 24) {
    float* ob = out + (size_t)b * 288 + li * 12;
    float4 w0, w1, w2;
    w0.x = acc[0]; w0.y = acc[1]; w0.z = acc[2]; w0.w = acc[3];
    w1.x = acc[4]; w1.y = acc[5]; w1.z = acc[6]; w1.w = acc[7];
    w2.x = acc[8]; w2.y = acc[9]; w2.z = acc[10]; w2.w = acc[11];
    *(float4*)(ob + 0) = w0;
    *(float4*)(ob + 4) = w1;
    *(float4*)(ob + 8) = w2;
  }
}

extern "C" void kernel_launch(void* const* d_in, const int* in_sizes, int n_in,
                              void* d_out, int out_size, void* d_ws, size_t ws_size,
                              hipStream_t stream) {
  const float* q = (const float*)d_in[0];
  const float* k = (const float*)d_in[1];
  // d_in[2] = v : unused by the reference
  const float* Wq = (const float*)d_in[3];
  const float* bq = (const float*)d_in[4];
  const float* Wk = (const float*)d_in[5];
  const float* bk = (const float*)d_in[6];
  const float* Wl = (const float*)d_in[7];
  const float* bl = (const float*)d_in[8];
  float* out = (float*)d_out;

  const int B = in_sizes[0] / (24 * 12);
  coattn_kernel<<<B, 64, 0, stream>>>(q, k, Wq, bq, Wk, bk, Wl, bl, out);
}